// Round 4
// baseline (776.514 us; speedup 1.0000x reference)
//
#include <hip/hip_runtime.h>
#include <math.h>

// SSIM, separable column-pipeline, 2 columns/thread.
// img1,img2: [32,3,512,512] fp32 -> scalar mean.
//
// ssim_kernel: block = 256 threads = full 512-col row tile, TH=64 output rows.
//  - per iteration stage one input row (522 cols incl. 5-px halo) as
//    interleaved (a,b) float2 pairs into double-buffered LDS; global loads
//    issued BEFORE the barrier, LDS writes after (latency spans the sync).
//  - each thread reads its 12-pair window as 6 ds_read_b128 and computes the
//    11-tap horizontal conv for its 2 columns (5 quantities, float2).
//  - vertical conv in registers: 11-slot x 5-quantity float2 accumulator
//    ring, compile-time ring indices; weight-0 tap ASSIGNS (no resets).
//  - fp32 reciprocal via v_rcp_f32 instead of IEEE divide.
//  - per-thread sum -> block reduce -> 1 float partial per block (768 total).
// reduce_kernel: single block sums 768 partials in double, writes mean.
//
// Round-2 lesson: keep VGPR cap at 256 (launch_bounds min-waves=2); the
// 110-reg ring + window must not spill (watch WRITE_SIZE).

#define IH 512
#define IW 512
#define NCH 96            // 32*3 depthwise channels
#define TH 64             // output rows per block
#define NIT 77            // 7*11 staged h-rows (need TH+10=74; 3 wasted)
#define NE 522            // staged (a,b) pairs per row: 512 + 2*5 halo
#define C1f (0.01f * 0.01f)
#define C2f (0.03f * 0.03f)

struct Weights { float w[11]; };

__device__ __forceinline__ float ssim_px(float mu1, float mu2, float m11,
                                         float m22, float m12) {
    const float mu1s = mu1 * mu1;
    const float mu2s = mu2 * mu2;
    const float mu12 = mu1 * mu2;
    const float num = (2.f * mu12 + C1f) * (2.f * (m12 - mu12) + C2f);
    const float den = (mu1s + mu2s + C1f) * ((m11 - mu1s) + (m22 - mu2s) + C2f);
    return num * __builtin_amdgcn_rcpf(den);
}

__global__ __launch_bounds__(256, 2) void ssim_kernel(
    const float* __restrict__ img1, const float* __restrict__ img2,
    float* __restrict__ partial, Weights wt)
{
    __shared__ __align__(16) float2 sAB[2][NE];   // (a,b) interleaved pairs
    __shared__ float wave_sums[4];

    const int tid = threadIdx.x;
    const int bx  = blockIdx.x;
    const int ty  = bx & 7;          // 8 row tiles
    const int ch  = bx >> 3;         // 96 channels

    const int row_out0 = ty * TH;
    const int row0     = row_out0 - 5;   // staged row r -> global row row0+r
    const float* __restrict__ p1 = img1 + (size_t)ch * (IH * IW);
    const float* __restrict__ p2 = img2 + (size_t)ch * (IH * IW);

    // staged entry indices for this thread (entry i <-> global col i-5)
    const int i0 = tid;                    // cols -5..250  (invalid for tid<5)
    const int i1 = tid + 256;              // cols 251..506 (always valid)
    const int i2 = tid + 512;              // cols 507..516 (tid<10 stages;
                                           //  valid only tid<5)
    const int cc0 = (tid < 5) ? 0 : (i0 - 5);          // clamped col
    const int cc2 = (i2 - 5 < IW) ? (i2 - 5) : (IW-1); // clamped col
    const int c1  = i1 - 5;

    auto load_row = [&](int r, float2& e0, float2& e1, float2& e2) {
        const int gr = row0 + r;                       // wave-uniform
        e0 = make_float2(0.f, 0.f);
        e1 = make_float2(0.f, 0.f);
        e2 = make_float2(0.f, 0.f);
        if ((unsigned)gr < (unsigned)IH) {             // uniform branch
            const size_t ro = (size_t)gr * IW;
            float a0 = p1[ro + cc0], b0 = p2[ro + cc0];
            e0 = make_float2((tid < 5) ? 0.f : a0, (tid < 5) ? 0.f : b0);
            e1 = make_float2(p1[ro + c1], p2[ro + c1]);
            if (tid < 10) {
                float a2 = p1[ro + cc2], b2 = p2[ro + cc2];
                e2 = make_float2((tid < 5) ? a2 : 0.f, (tid < 5) ? b2 : 0.f);
            }
        }
    };

    auto write_row = [&](int r, const float2& e0, const float2& e1,
                         const float2& e2) {
        const int p = r & 1;
        sAB[p][i0] = e0;
        sAB[p][i1] = e1;
        if (tid < 10) sAB[p][i2] = e2;
    };

    // accumulator ring: slot s holds output row o with o % 11 == s (.x=col0,.y=col1)
    float2 acc0[11], acc1[11], acc2[11], acc3[11], acc4[11];
    #pragma unroll
    for (int s = 0; s < 11; ++s) {
        acc0[s] = acc1[s] = acc2[s] = acc3[s] = acc4[s] = make_float2(0.f, 0.f);
    }

    float tsum = 0.f;

    {   // prologue: stage row 0
        float2 e0, e1, e2;
        load_row(0, e0, e1, e2);
        write_row(0, e0, e1, e2);
    }

    for (int g = 0; g < 7; ++g) {
        #pragma unroll
        for (int j = 0; j < 11; ++j) {
            const int r = g * 11 + j;      // staged row being consumed, 0..76

            // global loads for next row BEFORE the barrier
            float2 e0, e1, e2;
            load_row(r + 1, e0, e1, e2);

            __syncthreads();               // prev compute done -> safe to write
            write_row(r + 1, e0, e1, e2);

            const int p = (g + j) & 1;     // parity of r

            // ---- 12-pair window: 6 x ds_read_b128 ----
            const float4* __restrict__ q4 =
                reinterpret_cast<const float4*>(&sAB[p][2 * tid]);
            const float4 t0 = q4[0], t1 = q4[1], t2 = q4[2];
            const float4 t3 = q4[3], t4 = q4[4], t5 = q4[5];
            const float2 P[12] = {
                {t0.x, t0.y}, {t0.z, t0.w}, {t1.x, t1.y}, {t1.z, t1.w},
                {t2.x, t2.y}, {t2.z, t2.w}, {t3.x, t3.y}, {t3.z, t3.w},
                {t4.x, t4.y}, {t4.z, t4.w}, {t5.x, t5.y}, {t5.z, t5.w}};

            // ---- horizontal 11-tap conv, 2 columns ----
            float2 hx = {0.f, 0.f}, hy = {0.f, 0.f}, hxx = {0.f, 0.f},
                   hyy = {0.f, 0.f}, hxy = {0.f, 0.f};
            #pragma unroll
            for (int k = 0; k < 11; ++k) {
                const float wk = wt.w[k];
                {   // column 0 (= 2*tid) uses pairs k
                    const float a = P[k].x, b = P[k].y;
                    const float ta = wk * a, tb = wk * b;
                    hx.x += ta; hy.x += tb;
                    hxx.x += ta * a; hyy.x += tb * b; hxy.x += ta * b;
                }
                {   // column 1 (= 2*tid+1) uses pairs k+1
                    const float a = P[k + 1].x, b = P[k + 1].y;
                    const float ta = wk * a, tb = wk * b;
                    hx.y += ta; hy.y += tb;
                    hxx.y += ta * a; hyy.y += tb * b; hxy.y += ta * b;
                }
            }

            // ---- vertical conv: scatter into ring; wi==0 assigns ----
            #pragma unroll
            for (int s = 0; s < 11; ++s) {
                const int wi = (j - s + 11) % 11;   // compile-time
                const float wk = wt.w[wi];
                if (wi == 0) {
                    acc0[s].x = wk * hx.x;  acc0[s].y = wk * hx.y;
                    acc1[s].x = wk * hy.x;  acc1[s].y = wk * hy.y;
                    acc2[s].x = wk * hxx.x; acc2[s].y = wk * hxx.y;
                    acc3[s].x = wk * hyy.x; acc3[s].y = wk * hyy.y;
                    acc4[s].x = wk * hxy.x; acc4[s].y = wk * hxy.y;
                } else {
                    acc0[s].x += wk * hx.x;  acc0[s].y += wk * hx.y;
                    acc1[s].x += wk * hy.x;  acc1[s].y += wk * hy.y;
                    acc2[s].x += wk * hxx.x; acc2[s].y += wk * hxx.y;
                    acc3[s].x += wk * hyy.x; acc3[s].y += wk * hyy.y;
                    acc4[s].x += wk * hxy.x; acc4[s].y += wk * hxy.y;
                }
            }

            // ---- emit output row o = r-10 (slot (j+1)%11) ----
            const int se = (j + 1) % 11;            // compile-time
            const int o = r - 10;
            const bool valid = (o >= 0) && (o < TH);
            const float sv =
                ssim_px(acc0[se].x, acc1[se].x, acc2[se].x, acc3[se].x,
                        acc4[se].x) +
                ssim_px(acc0[se].y, acc1[se].y, acc2[se].y, acc3[se].y,
                        acc4[se].y);
            tsum += valid ? sv : 0.f;
        }
    }

    // ---- block reduction ----
    #pragma unroll
    for (int off = 32; off > 0; off >>= 1)
        tsum += __shfl_down(tsum, off);
    if ((tid & 63) == 0) wave_sums[tid >> 6] = tsum;
    __syncthreads();
    if (tid == 0) {
        partial[blockIdx.x] =
            wave_sums[0] + wave_sums[1] + wave_sums[2] + wave_sums[3];
    }
}

__global__ __launch_bounds__(256) void reduce_kernel(
    const float* __restrict__ partial, int n, float* __restrict__ out,
    double inv_count)
{
    __shared__ double wave_sums[4];
    const int tid = threadIdx.x;
    double s = 0.0;
    for (int i = tid; i < n; i += 256) s += (double)partial[i];
    #pragma unroll
    for (int off = 32; off > 0; off >>= 1)
        s += __shfl_down(s, off);
    if ((tid & 63) == 0) wave_sums[tid >> 6] = s;
    __syncthreads();
    if (tid == 0) {
        out[0] = (float)((wave_sums[0] + wave_sums[1] +
                          wave_sums[2] + wave_sums[3]) * inv_count);
    }
}

extern "C" void kernel_launch(void* const* d_in, const int* in_sizes, int n_in,
                              void* d_out, int out_size, void* d_ws, size_t ws_size,
                              hipStream_t stream)
{
    const float* img1 = (const float*)d_in[0];
    const float* img2 = (const float*)d_in[1];
    float* out = (float*)d_out;
    float* partial = (float*)d_ws;   // 768 floats = 3 KB scratch

    // Gaussian window (ws=11, sigma=1.5) in fp32, matching the reference
    Weights wt;
    {
        float s = 0.f;
        for (int i = 0; i < 11; ++i) {
            const float d = (float)(i - 5);
            wt.w[i] = expf(-(d * d) / 4.5f);
            s += wt.w[i];
        }
        for (int i = 0; i < 11; ++i) wt.w[i] /= s;
    }

    const int nblocks = NCH * 8;     // 768

    ssim_kernel<<<nblocks, 256, 0, stream>>>(img1, img2, partial, wt);

    const double inv_count = 1.0 / ((double)NCH * IH * IW);
    reduce_kernel<<<1, 256, 0, stream>>>(partial, nblocks, out, inv_count);
}

// Round 5
// 428.272 us; speedup vs baseline: 1.8131x; 1.8131x over previous
//
#include <hip/hip_runtime.h>
#include <math.h>

// SSIM, separable column-pipeline, 2 columns/thread.
// img1,img2: [32,3,512,512] fp32 -> scalar mean.
//
// ssim_kernel: block = 256 threads = full 512-col row tile, TH=64 output rows.
//  - per iteration stage one input row (522 cols incl. 5-px halo) as
//    interleaved (a,b) float2 pairs into double-buffered LDS; global loads
//    issued BEFORE the barrier, LDS writes after (latency spans the sync).
//  - each thread reads its 12-pair window as 6 ds_read_b128 and computes the
//    11-tap horizontal conv for its 2 columns (5 quantities, float2).
//  - vertical conv in registers: 11-slot x 5-quantity float2 accumulator
//    ring, compile-time ring indices; weight-0 tap ASSIGNS (no resets).
//  - fp32 reciprocal via v_rcp_f32 instead of IEEE divide.
//  - per-thread sum -> block reduce -> 1 float partial per block (768 total).
// reduce_kernel: single block sums 768 partials in double, writes mean.
//
// VGPR-cap lesson (rounds 2/4): on this toolchain __launch_bounds__(256,N)
// caps VGPRs at 256/N: (256,4)->64, (256,2)->128 -- both spilled the ring
// (WRITE_SIZE 711 MB / 623 MB). The ~170-reg live state needs (256,1).

#define IH 512
#define IW 512
#define NCH 96            // 32*3 depthwise channels
#define TH 64             // output rows per block
#define NIT 77            // 7*11 staged h-rows (need TH+10=74; 3 wasted)
#define NE 522            // staged (a,b) pairs per row: 512 + 2*5 halo
#define C1f (0.01f * 0.01f)
#define C2f (0.03f * 0.03f)

struct Weights { float w[11]; };

__device__ __forceinline__ float ssim_px(float mu1, float mu2, float m11,
                                         float m22, float m12) {
    const float mu1s = mu1 * mu1;
    const float mu2s = mu2 * mu2;
    const float mu12 = mu1 * mu2;
    const float num = (2.f * mu12 + C1f) * (2.f * (m12 - mu12) + C2f);
    const float den = (mu1s + mu2s + C1f) * ((m11 - mu1s) + (m22 - mu2s) + C2f);
    return num * __builtin_amdgcn_rcpf(den);
}

__global__ __launch_bounds__(256, 1) void ssim_kernel(
    const float* __restrict__ img1, const float* __restrict__ img2,
    float* __restrict__ partial, Weights wt)
{
    __shared__ __align__(16) float2 sAB[2][NE];   // (a,b) interleaved pairs
    __shared__ float wave_sums[4];

    const int tid = threadIdx.x;
    const int bx  = blockIdx.x;
    const int ty  = bx & 7;          // 8 row tiles
    const int ch  = bx >> 3;         // 96 channels

    const int row_out0 = ty * TH;
    const int row0     = row_out0 - 5;   // staged row r -> global row row0+r
    const float* __restrict__ p1 = img1 + (size_t)ch * (IH * IW);
    const float* __restrict__ p2 = img2 + (size_t)ch * (IH * IW);

    // staged entry indices for this thread (entry i <-> global col i-5)
    const int i0 = tid;                    // cols -5..250  (invalid for tid<5)
    const int i1 = tid + 256;              // cols 251..506 (always valid)
    const int i2 = tid + 512;              // cols 507..516 (tid<10 stages;
                                           //  valid only tid<5)
    const int cc0 = (tid < 5) ? 0 : (i0 - 5);          // clamped col
    const int cc2 = (i2 - 5 < IW) ? (i2 - 5) : (IW-1); // clamped col
    const int c1  = i1 - 5;

    auto load_row = [&](int r, float2& e0, float2& e1, float2& e2) {
        const int gr = row0 + r;                       // wave-uniform
        e0 = make_float2(0.f, 0.f);
        e1 = make_float2(0.f, 0.f);
        e2 = make_float2(0.f, 0.f);
        if ((unsigned)gr < (unsigned)IH) {             // uniform branch
            const size_t ro = (size_t)gr * IW;
            float a0 = p1[ro + cc0], b0 = p2[ro + cc0];
            e0 = make_float2((tid < 5) ? 0.f : a0, (tid < 5) ? 0.f : b0);
            e1 = make_float2(p1[ro + c1], p2[ro + c1]);
            if (tid < 10) {
                float a2 = p1[ro + cc2], b2 = p2[ro + cc2];
                e2 = make_float2((tid < 5) ? a2 : 0.f, (tid < 5) ? b2 : 0.f);
            }
        }
    };

    auto write_row = [&](int r, const float2& e0, const float2& e1,
                         const float2& e2) {
        const int p = r & 1;
        sAB[p][i0] = e0;
        sAB[p][i1] = e1;
        if (tid < 10) sAB[p][i2] = e2;
    };

    // accumulator ring: slot s holds output row o with o % 11 == s (.x=col0,.y=col1)
    float2 acc0[11], acc1[11], acc2[11], acc3[11], acc4[11];
    #pragma unroll
    for (int s = 0; s < 11; ++s) {
        acc0[s] = acc1[s] = acc2[s] = acc3[s] = acc4[s] = make_float2(0.f, 0.f);
    }

    float tsum = 0.f;

    {   // prologue: stage row 0
        float2 e0, e1, e2;
        load_row(0, e0, e1, e2);
        write_row(0, e0, e1, e2);
    }

    for (int g = 0; g < 7; ++g) {
        #pragma unroll
        for (int j = 0; j < 11; ++j) {
            const int r = g * 11 + j;      // staged row being consumed, 0..76

            // global loads for next row BEFORE the barrier
            float2 e0, e1, e2;
            load_row(r + 1, e0, e1, e2);

            __syncthreads();               // prev compute done -> safe to write
            write_row(r + 1, e0, e1, e2);

            const int p = (g + j) & 1;     // parity of r

            // ---- 12-pair window: 6 x ds_read_b128 ----
            const float4* __restrict__ q4 =
                reinterpret_cast<const float4*>(&sAB[p][2 * tid]);
            const float4 t0 = q4[0], t1 = q4[1], t2 = q4[2];
            const float4 t3 = q4[3], t4 = q4[4], t5 = q4[5];
            const float2 P[12] = {
                {t0.x, t0.y}, {t0.z, t0.w}, {t1.x, t1.y}, {t1.z, t1.w},
                {t2.x, t2.y}, {t2.z, t2.w}, {t3.x, t3.y}, {t3.z, t3.w},
                {t4.x, t4.y}, {t4.z, t4.w}, {t5.x, t5.y}, {t5.z, t5.w}};

            // ---- horizontal 11-tap conv, 2 columns ----
            float2 hx = {0.f, 0.f}, hy = {0.f, 0.f}, hxx = {0.f, 0.f},
                   hyy = {0.f, 0.f}, hxy = {0.f, 0.f};
            #pragma unroll
            for (int k = 0; k < 11; ++k) {
                const float wk = wt.w[k];
                {   // column 0 (= 2*tid) uses pairs k
                    const float a = P[k].x, b = P[k].y;
                    const float ta = wk * a, tb = wk * b;
                    hx.x += ta; hy.x += tb;
                    hxx.x += ta * a; hyy.x += tb * b; hxy.x += ta * b;
                }
                {   // column 1 (= 2*tid+1) uses pairs k+1
                    const float a = P[k + 1].x, b = P[k + 1].y;
                    const float ta = wk * a, tb = wk * b;
                    hx.y += ta; hy.y += tb;
                    hxx.y += ta * a; hyy.y += tb * b; hxy.y += ta * b;
                }
            }

            // ---- vertical conv: scatter into ring; wi==0 assigns ----
            #pragma unroll
            for (int s = 0; s < 11; ++s) {
                const int wi = (j - s + 11) % 11;   // compile-time
                const float wk = wt.w[wi];
                if (wi == 0) {
                    acc0[s].x = wk * hx.x;  acc0[s].y = wk * hx.y;
                    acc1[s].x = wk * hy.x;  acc1[s].y = wk * hy.y;
                    acc2[s].x = wk * hxx.x; acc2[s].y = wk * hxx.y;
                    acc3[s].x = wk * hyy.x; acc3[s].y = wk * hyy.y;
                    acc4[s].x = wk * hxy.x; acc4[s].y = wk * hxy.y;
                } else {
                    acc0[s].x += wk * hx.x;  acc0[s].y += wk * hx.y;
                    acc1[s].x += wk * hy.x;  acc1[s].y += wk * hy.y;
                    acc2[s].x += wk * hxx.x; acc2[s].y += wk * hxx.y;
                    acc3[s].x += wk * hyy.x; acc3[s].y += wk * hyy.y;
                    acc4[s].x += wk * hxy.x; acc4[s].y += wk * hxy.y;
                }
            }

            // ---- emit output row o = r-10 (slot (j+1)%11) ----
            const int se = (j + 1) % 11;            // compile-time
            const int o = r - 10;
            const bool valid = (o >= 0) && (o < TH);
            const float sv =
                ssim_px(acc0[se].x, acc1[se].x, acc2[se].x, acc3[se].x,
                        acc4[se].x) +
                ssim_px(acc0[se].y, acc1[se].y, acc2[se].y, acc3[se].y,
                        acc4[se].y);
            tsum += valid ? sv : 0.f;
        }
    }

    // ---- block reduction ----
    #pragma unroll
    for (int off = 32; off > 0; off >>= 1)
        tsum += __shfl_down(tsum, off);
    if ((tid & 63) == 0) wave_sums[tid >> 6] = tsum;
    __syncthreads();
    if (tid == 0) {
        partial[blockIdx.x] =
            wave_sums[0] + wave_sums[1] + wave_sums[2] + wave_sums[3];
    }
}

__global__ __launch_bounds__(256) void reduce_kernel(
    const float* __restrict__ partial, int n, float* __restrict__ out,
    double inv_count)
{
    __shared__ double wave_sums[4];
    const int tid = threadIdx.x;
    double s = 0.0;
    for (int i = tid; i < n; i += 256) s += (double)partial[i];
    #pragma unroll
    for (int off = 32; off > 0; off >>= 1)
        s += __shfl_down(s, off);
    if ((tid & 63) == 0) wave_sums[tid >> 6] = s;
    __syncthreads();
    if (tid == 0) {
        out[0] = (float)((wave_sums[0] + wave_sums[1] +
                          wave_sums[2] + wave_sums[3]) * inv_count);
    }
}

extern "C" void kernel_launch(void* const* d_in, const int* in_sizes, int n_in,
                              void* d_out, int out_size, void* d_ws, size_t ws_size,
                              hipStream_t stream)
{
    const float* img1 = (const float*)d_in[0];
    const float* img2 = (const float*)d_in[1];
    float* out = (float*)d_out;
    float* partial = (float*)d_ws;   // 768 floats = 3 KB scratch

    // Gaussian window (ws=11, sigma=1.5) in fp32, matching the reference
    Weights wt;
    {
        float s = 0.f;
        for (int i = 0; i < 11; ++i) {
            const float d = (float)(i - 5);
            wt.w[i] = expf(-(d * d) / 4.5f);
            s += wt.w[i];
        }
        for (int i = 0; i < 11; ++i) wt.w[i] /= s;
    }

    const int nblocks = NCH * 8;     // 768

    ssim_kernel<<<nblocks, 256, 0, stream>>>(img1, img2, partial, wt);

    const double inv_count = 1.0 / ((double)NCH * IH * IW);
    reduce_kernel<<<1, 256, 0, stream>>>(partial, nblocks, out, inv_count);
}